// Round 3
// baseline (316.336 us; speedup 1.0000x reference)
//
#include <hip/hip_runtime.h>

// x volumes: [256,256,256] fp32. Row (d,h) = 256 floats = 64 float4.
// float4-unit offsets: d*16384 + h*64 + lane.
//
// Grid: 64 htiles (4 h-rows each, one per wave) x 64 d-chunks (4 deep)
// = 4096 blocks x 256 threads. Chunk of 4 chosen over 16: grid 4x larger
// -> 8 blocks/CU resident (32 waves/CU, full occupancy) vs 4 blocks/CU.
//
// d_ws layout: [0..255] double acc slots, [256] double-slot reused as
// uint ticket. All zeroed by hipMemsetAsync before launch.

#define NBLOCKS (64 * 64)

__global__ __launch_bounds__(256) void grad_loss_kernel(const float4* __restrict__ x1,
                                                        const float4* __restrict__ x2,
                                                        double* __restrict__ acc,
                                                        unsigned int* __restrict__ ticket,
                                                        float* __restrict__ out) {
    const int tid   = threadIdx.x;
    const int lane  = tid & 63;     // float4 position within the row
    const int hslot = tid >> 6;     // wave id -> which h row of the 4-tile
    const int htile = blockIdx.x & 63;
    const int dchk  = blockIdx.x >> 6;

    const int h  = 1 + htile * 4 + hslot;   // 1..256 (mask >254)
    const int d0 = 1 + dchk * 4;            // 1,5,...,253

    // per-voxel w-axis weights (0 = excluded border voxel, 2 = edge-replicated)
    float ww0, ww1, ww2, ww3;
    {
        const int wbase = 4 * lane;
        ww0 = (wbase + 0 == 0)   ? 0.0f : ((wbase + 0 == 1)   ? 2.0f : 1.0f);
        ww1 = (wbase + 1 == 1)   ? 2.0f : 1.0f;
        ww2 = (wbase + 2 == 254) ? 2.0f : 1.0f;
        ww3 = (wbase + 3 == 255) ? 0.0f : ((wbase + 3 == 254) ? 2.0f : 1.0f);
    }

    float val = 0.0f;

    if (h <= 254) {
        const float whf = (h == 1 || h == 254) ? 2.0f : 1.0f;
        const int rowbase = h * 64 + lane;

        // rolling window along d: a = row(d-1), b = row(d), c = row(d+1)
        float4 a1 = x1[(d0 - 1) * 16384 + rowbase];
        float4 b1 = x1[d0 * 16384 + rowbase];
        float4 a2 = x2[(d0 - 1) * 16384 + rowbase];
        float4 b2 = x2[d0 * 16384 + rowbase];

        const int dend = (d0 + 4 <= 255) ? (d0 + 4) : 255;  // d <= 254
        for (int d = d0; d < dend; ++d) {
            const int base = d * 16384 + rowbase;
            float4 c1 = x1[base + 16384];
            float4 u1 = x1[base - 64];
            float4 v1 = x1[base + 64];
            float4 c2 = x2[base + 16384];
            float4 u2 = x2[base - 64];
            float4 v2 = x2[base + 64];

            // shifted w-neighbors of the center rows via cross-lane shuffle
            float l1 = __shfl_up(b1.w, 1, 64);
            float r1 = __shfl_down(b1.x, 1, 64);
            float l2 = __shfl_up(b2.w, 1, 64);
            float r2 = __shfl_down(b2.x, 1, 64);

            float gw, gd, gh, m10, m11, m12, m13, m20, m21, m22, m23;

            gw = c1.x - a1.x; gd = v1.x - u1.x; gh = b1.y - l1;
            m10 = sqrtf(gw * gw + gd * gd + gh * gh + 1e-6f);
            gw = c1.y - a1.y; gd = v1.y - u1.y; gh = b1.z - b1.x;
            m11 = sqrtf(gw * gw + gd * gd + gh * gh + 1e-6f);
            gw = c1.z - a1.z; gd = v1.z - u1.z; gh = b1.w - b1.y;
            m12 = sqrtf(gw * gw + gd * gd + gh * gh + 1e-6f);
            gw = c1.w - a1.w; gd = v1.w - u1.w; gh = r1 - b1.z;
            m13 = sqrtf(gw * gw + gd * gd + gh * gh + 1e-6f);

            gw = c2.x - a2.x; gd = v2.x - u2.x; gh = b2.y - l2;
            m20 = sqrtf(gw * gw + gd * gd + gh * gh + 1e-6f);
            gw = c2.y - a2.y; gd = v2.y - u2.y; gh = b2.z - b2.x;
            m21 = sqrtf(gw * gw + gd * gd + gh * gh + 1e-6f);
            gw = c2.z - a2.z; gd = v2.z - u2.z; gh = b2.w - b2.y;
            m22 = sqrtf(gw * gw + gd * gd + gh * gh + 1e-6f);
            gw = c2.w - a2.w; gd = v2.w - u2.w; gh = r2 - b2.z;
            m23 = sqrtf(gw * gw + gd * gd + gh * gh + 1e-6f);

            float inner = ww0 * fabsf(m10 - m20)
                        + ww1 * fabsf(m11 - m21)
                        + ww2 * fabsf(m12 - m22)
                        + ww3 * fabsf(m13 - m23);

            const float wdf = (d == 1 || d == 254) ? 2.0f : 1.0f;
            val += wdf * whf * inner;

            a1 = b1; b1 = c1;
            a2 = b2; b2 = c2;
        }
    }

    // wave-64 reduction
    for (int off = 32; off > 0; off >>= 1)
        val += __shfl_down(val, off, 64);

    __shared__ float smem[4];
    __shared__ int is_last;
    const int lid = tid & 63;
    const int wid = tid >> 6;
    if (lid == 0) smem[wid] = val;
    __syncthreads();

    if (tid == 0) {
        float s = smem[0] + smem[1] + smem[2] + smem[3];
        atomicAdd(&acc[blockIdx.x & 255], (double)s);
        __threadfence();                            // make the add visible device-wide
        unsigned int old = atomicAdd(ticket, 1u);   // device-scope ticket
        is_last = (old == NBLOCKS - 1) ? 1 : 0;
    }
    __syncthreads();

    if (is_last) {
        // Coherent read of all 256 slots via atomic read-modify-write of 0.
        double v = atomicAdd(&acc[tid], 0.0);
        // block reduction over 256 doubles
        for (int off = 32; off > 0; off >>= 1)
            v += __shfl_down(v, off, 64);
        __shared__ double dmem[4];
        if (lid == 0) dmem[wid] = v;
        __syncthreads();
        if (tid == 0) {
            double s = dmem[0] + dmem[1] + dmem[2] + dmem[3];
            out[0] = (float)(s / 16777216.0);   // mean over 256^3
        }
    }
}

extern "C" void kernel_launch(void* const* d_in, const int* in_sizes, int n_in,
                              void* d_out, int out_size, void* d_ws, size_t ws_size,
                              hipStream_t stream) {
    const float4* x1 = (const float4*)d_in[0];
    const float4* x2 = (const float4*)d_in[1];
    float* out = (float*)d_out;
    double* acc = (double*)d_ws;                         // 256 doubles
    unsigned int* ticket = (unsigned int*)(acc + 256);   // 1 uint

    hipMemsetAsync(d_ws, 0, 256 * sizeof(double) + 64, stream);
    grad_loss_kernel<<<NBLOCKS, 256, 0, stream>>>(x1, x2, acc, ticket, out);
}

// Round 4
// 158.997 us; speedup vs baseline: 1.9896x; 1.9896x over previous
//
#include <hip/hip_runtime.h>

// x volumes: [256,256,256] fp32. Row (d,h) = 256 floats = 64 float4.
// float4-unit offsets: d*16384 + h*64 + lane.
//
// Grid: 64 htiles (4 h-rows each, one per wave) x 64 d-chunks (4 deep)
// = 4096 blocks x 256 threads -> 8 blocks/CU resident (full 32 waves/CU).
// R3 lesson: NO __threadfence / single-kernel fused finalize — the
// device-scope release fence forces per-block L2 writebacks (non-coherent
// per-XCD L2s), serializing the TCC and killing stencil reuse (2.0 -> 0.63
// TB/s). Cross-kernel visibility via dispatch boundary instead.

__global__ __launch_bounds__(256) void grad_loss_kernel(const float4* __restrict__ x1,
                                                        const float4* __restrict__ x2,
                                                        double* __restrict__ acc) {
    const int tid   = threadIdx.x;
    const int lane  = tid & 63;     // float4 position within the row
    const int hslot = tid >> 6;     // wave id -> which h row of the 4-tile
    const int htile = blockIdx.x & 63;
    const int dchk  = blockIdx.x >> 6;

    const int h  = 1 + htile * 4 + hslot;   // 1..256 (mask >254)
    const int d0 = 1 + dchk * 4;            // 1,5,...,253

    // per-voxel w-axis weights (0 = excluded border voxel, 2 = edge-replicated)
    float ww0, ww1, ww2, ww3;
    {
        const int wbase = 4 * lane;
        ww0 = (wbase + 0 == 0)   ? 0.0f : ((wbase + 0 == 1)   ? 2.0f : 1.0f);
        ww1 = (wbase + 1 == 1)   ? 2.0f : 1.0f;
        ww2 = (wbase + 2 == 254) ? 2.0f : 1.0f;
        ww3 = (wbase + 3 == 255) ? 0.0f : ((wbase + 3 == 254) ? 2.0f : 1.0f);
    }

    float val = 0.0f;

    if (h <= 254) {
        const float whf = (h == 1 || h == 254) ? 2.0f : 1.0f;
        const int rowbase = h * 64 + lane;

        // rolling window along d: a = row(d-1), b = row(d), c = row(d+1)
        float4 a1 = x1[(d0 - 1) * 16384 + rowbase];
        float4 b1 = x1[d0 * 16384 + rowbase];
        float4 a2 = x2[(d0 - 1) * 16384 + rowbase];
        float4 b2 = x2[d0 * 16384 + rowbase];

        const int dend = (d0 + 4 <= 255) ? (d0 + 4) : 255;  // d <= 254
        for (int d = d0; d < dend; ++d) {
            const int base = d * 16384 + rowbase;
            float4 c1 = x1[base + 16384];
            float4 u1 = x1[base - 64];
            float4 v1 = x1[base + 64];
            float4 c2 = x2[base + 16384];
            float4 u2 = x2[base - 64];
            float4 v2 = x2[base + 64];

            // shifted w-neighbors of the center rows via cross-lane shuffle
            float l1 = __shfl_up(b1.w, 1, 64);
            float r1 = __shfl_down(b1.x, 1, 64);
            float l2 = __shfl_up(b2.w, 1, 64);
            float r2 = __shfl_down(b2.x, 1, 64);

            float gw, gd, gh, m10, m11, m12, m13, m20, m21, m22, m23;

            gw = c1.x - a1.x; gd = v1.x - u1.x; gh = b1.y - l1;
            m10 = sqrtf(gw * gw + gd * gd + gh * gh + 1e-6f);
            gw = c1.y - a1.y; gd = v1.y - u1.y; gh = b1.z - b1.x;
            m11 = sqrtf(gw * gw + gd * gd + gh * gh + 1e-6f);
            gw = c1.z - a1.z; gd = v1.z - u1.z; gh = b1.w - b1.y;
            m12 = sqrtf(gw * gw + gd * gd + gh * gh + 1e-6f);
            gw = c1.w - a1.w; gd = v1.w - u1.w; gh = r1 - b1.z;
            m13 = sqrtf(gw * gw + gd * gd + gh * gh + 1e-6f);

            gw = c2.x - a2.x; gd = v2.x - u2.x; gh = b2.y - l2;
            m20 = sqrtf(gw * gw + gd * gd + gh * gh + 1e-6f);
            gw = c2.y - a2.y; gd = v2.y - u2.y; gh = b2.z - b2.x;
            m21 = sqrtf(gw * gw + gd * gd + gh * gh + 1e-6f);
            gw = c2.z - a2.z; gd = v2.z - u2.z; gh = b2.w - b2.y;
            m22 = sqrtf(gw * gw + gd * gd + gh * gh + 1e-6f);
            gw = c2.w - a2.w; gd = v2.w - u2.w; gh = r2 - b2.z;
            m23 = sqrtf(gw * gw + gd * gd + gh * gh + 1e-6f);

            float inner = ww0 * fabsf(m10 - m20)
                        + ww1 * fabsf(m11 - m21)
                        + ww2 * fabsf(m12 - m22)
                        + ww3 * fabsf(m13 - m23);

            const float wdf = (d == 1 || d == 254) ? 2.0f : 1.0f;
            val += wdf * whf * inner;

            a1 = b1; b1 = c1;
            a2 = b2; b2 = c2;
        }
    }

    // wave-64 reduction
    for (int off = 32; off > 0; off >>= 1)
        val += __shfl_down(val, off, 64);

    __shared__ float smem[4];
    const int lid = tid & 63;
    const int wid = tid >> 6;
    if (lid == 0) smem[wid] = val;
    __syncthreads();

    if (wid == 0) {
        float s = (lid < 4) ? smem[lid] : 0.0f;
        s += __shfl_down(s, 2, 64);
        s += __shfl_down(s, 1, 64);
        if (lid == 0)
            atomicAdd(&acc[blockIdx.x & 255], (double)s);   // no fence!
    }
}

__global__ void finalize_kernel(const double* __restrict__ acc, float* __restrict__ out) {
    double v = acc[threadIdx.x];   // 256 threads, one slot each
    for (int off = 32; off > 0; off >>= 1)
        v += __shfl_down(v, off, 64);

    __shared__ double smem[4];
    const int lid = threadIdx.x & 63;
    const int wid = threadIdx.x >> 6;
    if (lid == 0) smem[wid] = v;
    __syncthreads();

    if (threadIdx.x == 0) {
        double s = smem[0] + smem[1] + smem[2] + smem[3];
        out[0] = (float)(s / 16777216.0);   // mean over 256^3
    }
}

extern "C" void kernel_launch(void* const* d_in, const int* in_sizes, int n_in,
                              void* d_out, int out_size, void* d_ws, size_t ws_size,
                              hipStream_t stream) {
    const float4* x1 = (const float4*)d_in[0];
    const float4* x2 = (const float4*)d_in[1];
    float* out = (float*)d_out;
    double* acc = (double*)d_ws;   // 256 doubles = 2 KiB scratch

    hipMemsetAsync(d_ws, 0, 256 * sizeof(double), stream);
    grad_loss_kernel<<<64 * 64, 256, 0, stream>>>(x1, x2, acc);
    finalize_kernel<<<1, 256, 0, stream>>>(acc, out);
}

// Round 5
// 157.501 us; speedup vs baseline: 2.0085x; 1.0095x over previous
//
#include <hip/hip_runtime.h>

// x volumes: [256,256,256] fp32. Row (d,h) = 256 floats = 64 float4.
// float4-unit offset: d*16384 + h*64 + lane. float-unit: d*65536 + h*256 + 4*lane.
//
// Grid: 64 htiles (4 h-rows, one per wave) x 32 d-chunks (8 deep) = 2048 blocks.
// Depth-1 software pipeline: all operands for depth d+1 (c/u/v rows + w-edge
// scalars) are prefetched during depth d's compute. Edge scalars come from
// global (same cache lines as the row -> L1 hits) instead of __shfl: removes
// the dependent ds_bpermute (lgkmcnt ~120cy) from the critical path.
// R3 lesson: no __threadfence / fused finalize (per-XCD L2 writeback storm).
// R4 lesson: VGPR=32 left too few loads in flight -> latency-bound at 2.6 TB/s.

#define CHUNK 8

__global__ __launch_bounds__(256) void grad_loss_kernel(const float* __restrict__ xf1,
                                                        const float* __restrict__ xf2,
                                                        double* __restrict__ acc) {
    const float4* __restrict__ x1 = (const float4*)xf1;
    const float4* __restrict__ x2 = (const float4*)xf2;

    const int tid   = threadIdx.x;
    const int lane  = tid & 63;
    const int hslot = tid >> 6;
    const int htile = blockIdx.x & 63;
    const int dchk  = blockIdx.x >> 6;      // 0..31

    const int h  = 1 + htile * 4 + hslot;   // 1..256 (mask >254)
    const int d0 = 1 + dchk * CHUNK;        // 1,9,...,249 (tail d=255,256 weighted 0)

    // per-voxel w-axis weights (0 = excluded border voxel, 2 = edge-replicated)
    const int wbase = 4 * lane;
    const float ww0 = (wbase + 0 == 0)   ? 0.0f : 1.0f;
    const float ww1 = (wbase + 1 == 1)   ? 2.0f : 1.0f;
    const float ww2 = (wbase + 2 == 254) ? 2.0f : 1.0f;
    const float ww3 = (wbase + 3 == 255) ? 0.0f : 1.0f;

    float val = 0.0f;

    if (h <= 254) {
        const float whf = (h == 1 || h == 254) ? 2.0f : 1.0f;
        const int rowbase = h * 64 + lane;       // float4 units (without d)
        const int frow    = h * 256 + wbase;     // float units (without d)

        // prologue: depth-d0 operand set
        float4 a1 = x1[(d0 - 1) * 16384 + rowbase];
        float4 b1 = x1[d0 * 16384 + rowbase];
        float4 a2 = x2[(d0 - 1) * 16384 + rowbase];
        float4 b2 = x2[d0 * 16384 + rowbase];
        float  l1 = xf1[d0 * 65536 + frow - 1];
        float  r1 = xf1[d0 * 65536 + frow + 4];
        float  l2 = xf2[d0 * 65536 + frow - 1];
        float  r2 = xf2[d0 * 65536 + frow + 4];
        float4 c1 = x1[(d0 + 1) * 16384 + rowbase];
        float4 u1 = x1[d0 * 16384 + rowbase - 64];
        float4 v1 = x1[d0 * 16384 + rowbase + 64];
        float4 c2 = x2[(d0 + 1) * 16384 + rowbase];
        float4 u2 = x2[d0 * 16384 + rowbase - 64];
        float4 v2 = x2[d0 * 16384 + rowbase + 64];

        #pragma unroll
        for (int i = 0; i < CHUNK; ++i) {
            const int d = d0 + i;

            // prefetch the full depth-(d+1) operand set (clamped at the tail;
            // tail iterations get weight 0 so values only need to be finite)
            float4 nc1, nu1, nv1, nc2, nu2, nv2;
            float  nl1, nr1, nl2, nr2;
            if (i < CHUNK - 1) {
                const int dn = (d + 1 <= 254) ? (d + 1) : 254;
                const int nb = dn * 16384 + rowbase;
                const int nf = dn * 65536 + frow;
                nc1 = x1[nb + 16384];
                nu1 = x1[nb - 64];
                nv1 = x1[nb + 64];
                nl1 = xf1[nf - 1];
                nr1 = xf1[nf + 4];
                nc2 = x2[nb + 16384];
                nu2 = x2[nb - 64];
                nv2 = x2[nb + 64];
                nl2 = xf2[nf - 1];
                nr2 = xf2[nf + 4];
            }

            float gw, gd, gh;
            gw = c1.x - a1.x; gd = v1.x - u1.x; gh = b1.y - l1;
            float m10 = __builtin_amdgcn_sqrtf(gw * gw + gd * gd + gh * gh + 1e-6f);
            gw = c1.y - a1.y; gd = v1.y - u1.y; gh = b1.z - b1.x;
            float m11 = __builtin_amdgcn_sqrtf(gw * gw + gd * gd + gh * gh + 1e-6f);
            gw = c1.z - a1.z; gd = v1.z - u1.z; gh = b1.w - b1.y;
            float m12 = __builtin_amdgcn_sqrtf(gw * gw + gd * gd + gh * gh + 1e-6f);
            gw = c1.w - a1.w; gd = v1.w - u1.w; gh = r1 - b1.z;
            float m13 = __builtin_amdgcn_sqrtf(gw * gw + gd * gd + gh * gh + 1e-6f);

            gw = c2.x - a2.x; gd = v2.x - u2.x; gh = b2.y - l2;
            float m20 = __builtin_amdgcn_sqrtf(gw * gw + gd * gd + gh * gh + 1e-6f);
            gw = c2.y - a2.y; gd = v2.y - u2.y; gh = b2.z - b2.x;
            float m21 = __builtin_amdgcn_sqrtf(gw * gw + gd * gd + gh * gh + 1e-6f);
            gw = c2.z - a2.z; gd = v2.z - u2.z; gh = b2.w - b2.y;
            float m22 = __builtin_amdgcn_sqrtf(gw * gw + gd * gd + gh * gh + 1e-6f);
            gw = c2.w - a2.w; gd = v2.w - u2.w; gh = r2 - b2.z;
            float m23 = __builtin_amdgcn_sqrtf(gw * gw + gd * gd + gh * gh + 1e-6f);

            float inner = ww0 * fabsf(m10 - m20)
                        + ww1 * fabsf(m11 - m21)
                        + ww2 * fabsf(m12 - m22)
                        + ww3 * fabsf(m13 - m23);

            const float wdf = (d > 254) ? 0.0f : ((d == 1 || d == 254) ? 2.0f : 1.0f);
            val += wdf * whf * inner;

            if (i < CHUNK - 1) {
                a1 = b1; b1 = c1; c1 = nc1; u1 = nu1; v1 = nv1; l1 = nl1; r1 = nr1;
                a2 = b2; b2 = c2; c2 = nc2; u2 = nu2; v2 = nv2; l2 = nl2; r2 = nr2;
            }
        }
    }

    // wave-64 reduction
    for (int off = 32; off > 0; off >>= 1)
        val += __shfl_down(val, off, 64);

    __shared__ float smem[4];
    const int lid = tid & 63;
    const int wid = tid >> 6;
    if (lid == 0) smem[wid] = val;
    __syncthreads();

    if (wid == 0) {
        float s = (lid < 4) ? smem[lid] : 0.0f;
        s += __shfl_down(s, 2, 64);
        s += __shfl_down(s, 1, 64);
        if (lid == 0)
            atomicAdd(&acc[blockIdx.x & 255], (double)s);   // no fence!
    }
}

__global__ void finalize_kernel(const double* __restrict__ acc, float* __restrict__ out) {
    double v = acc[threadIdx.x];   // 256 threads, one slot each
    for (int off = 32; off > 0; off >>= 1)
        v += __shfl_down(v, off, 64);

    __shared__ double smem[4];
    const int lid = threadIdx.x & 63;
    const int wid = threadIdx.x >> 6;
    if (lid == 0) smem[wid] = v;
    __syncthreads();

    if (threadIdx.x == 0) {
        double s = smem[0] + smem[1] + smem[2] + smem[3];
        out[0] = (float)(s / 16777216.0);   // mean over 256^3
    }
}

extern "C" void kernel_launch(void* const* d_in, const int* in_sizes, int n_in,
                              void* d_out, int out_size, void* d_ws, size_t ws_size,
                              hipStream_t stream) {
    const float* x1 = (const float*)d_in[0];
    const float* x2 = (const float*)d_in[1];
    float* out = (float*)d_out;
    double* acc = (double*)d_ws;   // 256 doubles = 2 KiB scratch

    hipMemsetAsync(d_ws, 0, 256 * sizeof(double), stream);
    grad_loss_kernel<<<64 * 32, 256, 0, stream>>>(x1, x2, acc);
    finalize_kernel<<<1, 256, 0, stream>>>(acc, out);
}